// Round 3
// baseline (246.396 us; speedup 1.0000x reference)
//
#include <hip/hip_runtime.h>
#include <math.h>

// Problem constants
#define NPOS   65536        // 16*64*64 positions
#define NE     1024         // codebook size
#define EDIM   64
#define HW     4096         // 64*64
#define BETA   0.25

// Output layout (floats) in d_out, reference return order:
// loss(1), z_q_st(16*64*64*64), perplexity(1), min_encodings(65536*1024), indices(65536)
#define OUT_LOSS 0LL
#define OUT_ZQ   1LL
#define OUT_PERP 4194305LL
#define OUT_ENC  4194306LL
#define OUT_IDX  71303170LL

// Keep a float in a VGPR; compiler cannot rematerialize/sink the producing load.
#define PIN(x) asm volatile("" : "+v"(x))

// numpy pairwise_sum for n=64 (8 accumulators, stride 8, tree combine) of squares.
// Squares are rounded separately (contract off) to match np: tmp = v**2; sum(tmp).
__device__ __forceinline__ float pairwise_sum_sq64(const float v[64]) {
#pragma clang fp contract(off)
    float r[8];
#pragma unroll
    for (int k = 0; k < 8; ++k) r[k] = v[k] * v[k];
#pragma unroll
    for (int i = 8; i < 64; i += 8) {
#pragma unroll
        for (int k = 0; k < 8; ++k) {
            float s = v[i + k] * v[i + k];
            r[k] = r[k] + s;
        }
    }
    return ((r[0] + r[1]) + (r[2] + r[3])) + ((r[4] + r[5]) + (r[6] + r[7]));
}

// K0: codebook norms + zero counts + zero loss accumulator
__global__ void vq_prep(const float* __restrict__ emb, float* __restrict__ enorm,
                        int* __restrict__ counts, double* __restrict__ lacc) {
    int t = blockIdx.x * 256 + threadIdx.x;   // 0..1023
    if (t < NE) {
        float v[64];
#pragma unroll
        for (int c = 0; c < 64; ++c) v[c] = emb[t * 64 + c];
        enorm[t] = pairwise_sum_sq64(v);
        counts[t] = 0;
    }
    if (t == 0) *lacc = 0.0;
}

// K1: main. grid = 1024 blocks x 256 threads.
// Block handles 64 consecutive positions (one lane each); 4 waves split the
// 1024 codes into 4 chunks of 256 (wave-uniform j -> s_load of codebook rows).
__global__ __launch_bounds__(256, 4)
void vq_main(const float* __restrict__ z, const float* __restrict__ emb,
             const float* __restrict__ enorm, int* __restrict__ counts,
             double* __restrict__ lacc, float* __restrict__ out) {
    __shared__ float dl[256];
    __shared__ int   il[256];
    __shared__ int   fidx[64];

    const int tid = threadIdx.x;
    const int l   = tid & 63;        // lane = position within block
    const int w   = tid >> 6;        // wave = codebook chunk
    const int n0  = blockIdx.x * 64; // first position of block (same image b)
    const int b   = n0 >> 12;
    const int hw0 = n0 & 4095;
    const long long zoff = (long long)b * (64LL * HW) + hw0 + l;

    // load this position's 64-dim vector (coalesced across lanes per channel)
    // and PIN each value into a VGPR so the compiler cannot sink the loads
    // into the code loop (R2 disasm evidence: VGPR_Count=40 => zv was reloaded).
    float zv[64];
#pragma unroll
    for (int c = 0; c < 64; ++c) zv[c] = z[zoff + (long long)c * HW];
#pragma unroll
    for (int c = 0; c < 64; ++c) PIN(zv[c]);

    const float szn = pairwise_sum_sq64(zv);

    // wave-uniform chunk base => codebook rows come in via s_load
    const int jbase = __builtin_amdgcn_readfirstlane(w * 256);

    float best = 3.4e38f;
    int   bi   = jbase;
#pragma unroll 2
    for (int jj = 0; jj < 256; ++jj) {
        const int j = __builtin_amdgcn_readfirstlane(jbase + jj);
        const float* __restrict__ erow = emb + j * 64;
        // BLAS sgemm micro-kernel order: sequential k, single accumulator, FMA
        float acc = 0.0f;
#pragma unroll
        for (int c = 0; c < 64; ++c) acc = fmaf(zv[c], erow[c], acc);
        // dist = (||z||^2 + ||e||^2) - 2*dot  (2*acc exact => fma-fusion harmless)
        float dj = (szn + enorm[j]) - 2.0f * acc;
        if (dj < best) { best = dj; bi = j; }   // strict < : first-min wins
    }
    dl[tid] = best;
    il[tid] = bi;
    __syncthreads();

    // cross-wave argmin reduce (ascending chunk order keeps lowest index on ties)
    if (w == 0) {
        float bd = dl[l];
        int   bx = il[l];
#pragma unroll
        for (int ww = 1; ww < 4; ++ww) {
            float dw = dl[ww * 64 + l];
            int   iw = il[ww * 64 + l];
            if (dw < bd) { bd = dw; bx = iw; }
        }
        fidx[l] = bx;
        atomicAdd(&counts[bx], 1);
        out[OUT_IDX + n0 + l] = (float)bx;    // indices as f32 values
    }
    __syncthreads();

    // one-hot rows: 64 rows x 1024 floats, float2 stores (base is 8B-aligned only)
    {
        float2* __restrict__ enc = (float2*)(out + OUT_ENC);
        const int c0 = tid * 2;
        const int c1 = (tid + 256) * 2;
        for (int r = 0; r < 64; ++r) {
            const int ir = fidx[r];
            const long long rowb = (long long)(n0 + r) * 512;
            float2 v0, v1;
            v0.x = (ir == c0)     ? 1.0f : 0.0f;
            v0.y = (ir == c0 + 1) ? 1.0f : 0.0f;
            v1.x = (ir == c1)     ? 1.0f : 0.0f;
            v1.y = (ir == c1 + 1) ? 1.0f : 0.0f;
            enc[rowb + tid]       = v0;
            enc[rowb + 256 + tid] = v1;
        }
    }

    // z_q_st = z + (z_q - z)  (two rounded f32 ops, same as reference).
    // thread (w,l): position l, channels w*16..w*16+15, using register zv
    // (same bits as the global values). Compile-time ww dispatch keeps zv
    // indexing static (rule #20); w is wave-uniform so no divergence cost.
    const int myidx = fidx[l];
    double acc = 0.0;
#pragma unroll
    for (int ww = 0; ww < 4; ++ww) {
        if (w == ww) {
#pragma unroll
            for (int k = 0; k < 16; ++k) {
                const int c = ww * 16 + k;          // compile-time
                const float zc = zv[c];
                const float ec = emb[myidx * 64 + c];
                const float t  = __fsub_rn(ec, zc);   // z_q - z
                const float o  = __fadd_rn(zc, t);    // z + (z_q - z)
                out[OUT_ZQ + (long long)b * (64LL * HW) + (long long)c * HW + hw0 + l] = o;
                const float s = __fmul_rn(t, t);      // (z_q - z)^2 rounded f32
                acc += (double)s;
            }
        }
    }
    // wave-level f64 reduce, one atomic per wave
#pragma unroll
    for (int off = 32; off > 0; off >>= 1) acc += __shfl_down(acc, off);
    if (l == 0) atomicAdd(lacc, acc);
}

// K2: perplexity + loss finalize. 1 block x 1024 threads.
__global__ void vq_finalize(const int* __restrict__ counts,
                            const double* __restrict__ lacc,
                            float* __restrict__ out) {
    __shared__ float red[1024];
    const int t = threadIdx.x;
    const float p = (float)counts[t] * (1.0f / 65536.0f); // exact (count int, /2^16)
    const float term = p * logf(p + 1e-10f);
    red[t] = term;
    __syncthreads();
    for (int s = 512; s > 0; s >>= 1) {
        if (t < s) red[t] += red[t + s];
        __syncthreads();
    }
    if (t == 0) {
        out[OUT_PERP] = expf(-red[0]);
        out[OUT_LOSS] = (float)(BETA * (*lacc / 4194304.0));
    }
}

extern "C" void kernel_launch(void* const* d_in, const int* in_sizes, int n_in,
                              void* d_out, int out_size, void* d_ws, size_t ws_size,
                              hipStream_t stream) {
    const float* z   = (const float*)d_in[0];   // (16,64,64,64) f32
    const float* emb = (const float*)d_in[1];   // (1024,64) f32
    float* out = (float*)d_out;

    double* lacc  = (double*)d_ws;
    int*    cnts  = (int*)((char*)d_ws + 16);
    float*  enorm = (float*)((char*)d_ws + 16 + NE * sizeof(int));

    vq_prep<<<4, 256, 0, stream>>>(emb, enorm, cnts, lacc);
    vq_main<<<1024, 256, 0, stream>>>(z, emb, enorm, cnts, lacc, out);
    vq_finalize<<<1, 1024, 0, stream>>>(cnts, lacc, out);
}

// Round 4
// 214.854 us; speedup vs baseline: 1.1468x; 1.1468x over previous
//
#include <hip/hip_runtime.h>
#include <math.h>

// Problem constants
#define NPOS   65536        // 16*64*64 positions
#define NE     1024         // codebook size
#define EDIM   64
#define HW     4096         // 64*64
#define BETA   0.25

// Output layout (floats) in d_out, reference return order:
// loss(1), z_q_st(16*64*64*64), perplexity(1), min_encodings(65536*1024), indices(65536)
#define OUT_LOSS 0LL
#define OUT_ZQ   1LL
#define OUT_PERP 4194305LL
#define OUT_ENC  4194306LL
#define OUT_IDX  71303170LL

// numpy pairwise_sum for n=64 (8 accumulators, stride 8, tree combine) of squares.
// Squares are rounded separately (contract off) to match np: tmp = v**2; sum(tmp).
__device__ __forceinline__ float pairwise_sum_sq64(const float v[64]) {
#pragma clang fp contract(off)
    float r[8];
#pragma unroll
    for (int k = 0; k < 8; ++k) r[k] = v[k] * v[k];
#pragma unroll
    for (int i = 8; i < 64; i += 8) {
#pragma unroll
        for (int k = 0; k < 8; ++k) {
            float s = v[i + k] * v[i + k];
            r[k] = r[k] + s;
        }
    }
    return ((r[0] + r[1]) + (r[2] + r[3])) + ((r[4] + r[5]) + (r[6] + r[7]));
}

// K0: codebook norms + zero counts + zero loss accumulator
__global__ void vq_prep(const float* __restrict__ emb, float* __restrict__ enorm,
                        int* __restrict__ counts, double* __restrict__ lacc) {
    int t = blockIdx.x * 256 + threadIdx.x;   // 0..1023
    if (t < NE) {
        float v[64];
#pragma unroll
        for (int c = 0; c < 64; ++c) v[c] = emb[t * 64 + c];
        enorm[t] = pairwise_sum_sq64(v);
        counts[t] = 0;
    }
    if (t == 0) *lacc = 0.0;
}

// K1: main. grid = 1024 blocks x 256 threads.
// Block handles 64 consecutive positions (one lane each); 4 waves split the
// 1024 codes into 4 chunks of 256 (wave-uniform j -> s_load of codebook rows).
__global__ __launch_bounds__(256, 4)
void vq_main(const float* __restrict__ z, const float* __restrict__ emb,
             const float* __restrict__ enorm, int* __restrict__ counts,
             double* __restrict__ lacc, float* __restrict__ out) {
    __shared__ float dl[256];
    __shared__ int   il[256];
    __shared__ int   fidx[64];

    const int tid = threadIdx.x;
    const int l   = tid & 63;        // lane = position within block
    const int w   = tid >> 6;        // wave = codebook chunk
    const int n0  = blockIdx.x * 64; // first position of block (same image b)
    const int b   = n0 >> 12;
    const int hw0 = n0 & 4095;
    const int zoff = b * (64 * HW) + hw0 + l;      // element offset (fits in int)
    const long long zoffl = (long long)zoff;

    // Load this position's 64-dim vector (coalesced across lanes per channel).
    // Each zv[c] is DEFINED by a volatile asm global_load (saddr form: uniform
    // base in SGPR pair + per-lane 32-bit byte offset) -> the compiler cannot
    // rematerialize/reload it inside the code loop (R2/R3 evidence: VGPR=40/56,
    // i.e. zv was being re-fetched from L1 every one of the 256 iterations).
    float zv[64];
    {
        const int bytebase = zoff * 4;
#pragma unroll
        for (int c = 0; c < 64; ++c) {
            const int voff = bytebase + c * (HW * 4);
            asm volatile("global_load_dword %0, %1, %2"
                         : "=v"(zv[c])
                         : "v"(voff), "s"(z));
        }
        asm volatile("s_waitcnt vmcnt(0)" ::: "memory");
        __builtin_amdgcn_sched_barrier(0);   // rule #18: no hoisting past waitcnt
    }

    const float szn = pairwise_sum_sq64(zv);

    // wave-uniform chunk base => codebook rows come in via s_load
    const int jbase = __builtin_amdgcn_readfirstlane(w * 256);

    float best = 3.4e38f;
    int   bi   = jbase;
#pragma unroll 2
    for (int jj = 0; jj < 256; ++jj) {
        const int j = jbase + jj;
        const float* __restrict__ erow = emb + j * 64;
        // BLAS sgemm micro-kernel order: sequential k, single accumulator, FMA
        float acc = 0.0f;
#pragma unroll
        for (int c = 0; c < 64; ++c) acc = fmaf(zv[c], erow[c], acc);
        // dist = (||z||^2 + ||e||^2) - 2*dot  (2*acc exact => fma-fusion harmless)
        float dj = (szn + enorm[j]) - 2.0f * acc;
        if (dj < best) { best = dj; bi = j; }   // strict < : first-min wins
    }
    dl[tid] = best;
    il[tid] = bi;
    __syncthreads();

    // cross-wave argmin reduce (ascending chunk order keeps lowest index on ties)
    if (w == 0) {
        float bd = dl[l];
        int   bx = il[l];
#pragma unroll
        for (int ww = 1; ww < 4; ++ww) {
            float dw = dl[ww * 64 + l];
            int   iw = il[ww * 64 + l];
            if (dw < bd) { bd = dw; bx = iw; }
        }
        fidx[l] = bx;
        atomicAdd(&counts[bx], 1);
        out[OUT_IDX + n0 + l] = (float)bx;    // indices as f32 values
    }
    __syncthreads();

    // one-hot rows: 64 rows x 1024 floats, float2 stores (base is 8B-aligned only)
    {
        float2* __restrict__ enc = (float2*)(out + OUT_ENC);
        const int c0 = tid * 2;
        const int c1 = (tid + 256) * 2;
        for (int r = 0; r < 64; ++r) {
            const int ir = fidx[r];
            const long long rowb = (long long)(n0 + r) * 512;
            float2 v0, v1;
            v0.x = (ir == c0)     ? 1.0f : 0.0f;
            v0.y = (ir == c0 + 1) ? 1.0f : 0.0f;
            v1.x = (ir == c1)     ? 1.0f : 0.0f;
            v1.y = (ir == c1 + 1) ? 1.0f : 0.0f;
            enc[rowb + tid]       = v0;
            enc[rowb + 256 + tid] = v1;
        }
    }

    // z_q_st = z + (z_q - z)  (two rounded f32 ops, same as reference).
    // thread (w,l): position l, channels w*16..w*16+15, using register zv
    // (same bits as the global values). Compile-time ww dispatch keeps zv
    // indexing static (rule #20); w is wave-uniform so no divergence cost.
    const int myidx = fidx[l];
    double acc = 0.0;
#pragma unroll
    for (int ww = 0; ww < 4; ++ww) {
        if (w == ww) {
#pragma unroll
            for (int k = 0; k < 16; ++k) {
                const int c = ww * 16 + k;          // compile-time
                const float zc = zv[c];
                const float ec = emb[myidx * 64 + c];
                const float t  = __fsub_rn(ec, zc);   // z_q - z
                const float o  = __fadd_rn(zc, t);    // z + (z_q - z)
                out[OUT_ZQ + (long long)b * (64LL * HW) + (long long)c * HW + hw0 + l] = o;
                const float s = __fmul_rn(t, t);      // (z_q - z)^2 rounded f32
                acc += (double)s;
            }
        }
    }
    // wave-level f64 reduce, one atomic per wave
#pragma unroll
    for (int off = 32; off > 0; off >>= 1) acc += __shfl_down(acc, off);
    if (l == 0) atomicAdd(lacc, acc);
    (void)zoffl;
}

// K2: perplexity + loss finalize. 1 block x 1024 threads.
__global__ void vq_finalize(const int* __restrict__ counts,
                            const double* __restrict__ lacc,
                            float* __restrict__ out) {
    __shared__ float red[1024];
    const int t = threadIdx.x;
    const float p = (float)counts[t] * (1.0f / 65536.0f); // exact (count int, /2^16)
    const float term = p * logf(p + 1e-10f);
    red[t] = term;
    __syncthreads();
    for (int s = 512; s > 0; s >>= 1) {
        if (t < s) red[t] += red[t + s];
        __syncthreads();
    }
    if (t == 0) {
        out[OUT_PERP] = expf(-red[0]);
        out[OUT_LOSS] = (float)(BETA * (*lacc / 4194304.0));
    }
}

extern "C" void kernel_launch(void* const* d_in, const int* in_sizes, int n_in,
                              void* d_out, int out_size, void* d_ws, size_t ws_size,
                              hipStream_t stream) {
    const float* z   = (const float*)d_in[0];   // (16,64,64,64) f32
    const float* emb = (const float*)d_in[1];   // (1024,64) f32
    float* out = (float*)d_out;

    double* lacc  = (double*)d_ws;
    int*    cnts  = (int*)((char*)d_ws + 16);
    float*  enorm = (float*)((char*)d_ws + 16 + NE * sizeof(int));

    vq_prep<<<4, 256, 0, stream>>>(emb, enorm, cnts, lacc);
    vq_main<<<1024, 256, 0, stream>>>(z, emb, enorm, cnts, lacc, out);
    vq_finalize<<<1, 1024, 0, stream>>>(cnts, lacc, out);
}

// Round 5
// 197.172 us; speedup vs baseline: 1.2496x; 1.0897x over previous
//
#include <hip/hip_runtime.h>
#include <math.h>

// Problem constants
#define NPOS   65536        // 16*64*64 positions
#define NE     1024         // codebook size
#define EDIM   64
#define HW     4096         // 64*64
#define BETA   0.25

// Output layout (floats) in d_out, reference return order:
// loss(1), z_q_st(16*64*64*64), perplexity(1), min_encodings(65536*1024), indices(65536)
#define OUT_LOSS 0LL
#define OUT_ZQ   1LL
#define OUT_PERP 4194305LL
#define OUT_ENC  4194306LL
#define OUT_IDX  71303170LL

typedef __attribute__((ext_vector_type(16))) int i32x16;

// numpy pairwise_sum for n=64 (8 accumulators, stride 8, tree combine) of squares.
__device__ __forceinline__ float pairwise_sum_sq64(const float v[64]) {
#pragma clang fp contract(off)
    float r[8];
#pragma unroll
    for (int k = 0; k < 8; ++k) r[k] = v[k] * v[k];
#pragma unroll
    for (int i = 8; i < 64; i += 8) {
#pragma unroll
        for (int k = 0; k < 8; ++k) {
            float s = v[i + k] * v[i + k];
            r[k] = r[k] + s;
        }
    }
    return ((r[0] + r[1]) + (r[2] + r[3])) + ((r[4] + r[5]) + (r[6] + r[7]));
}

// K0: codebook norms + zero counts + zero loss accumulator
__global__ void vq_prep(const float* __restrict__ emb, float* __restrict__ enorm,
                        int* __restrict__ counts, double* __restrict__ lacc) {
    int t = blockIdx.x * 256 + threadIdx.x;   // 0..1023
    if (t < NE) {
        float v[64];
#pragma unroll
        for (int c = 0; c < 64; ++c) v[c] = emb[t * 64 + c];
        enorm[t] = pairwise_sum_sq64(v);
        counts[t] = 0;
    }
    if (t == 0) *lacc = 0.0;
}

// K1: main. grid = 1024 blocks x 256 threads.
// Block handles 64 consecutive positions (one lane each); 4 waves split the
// 1024 codes into 4 chunks of 256. Codebook rows are wave-uniform -> fetched
// into SGPRs via s_load_dwordx16 so the j-loop needs ~zero extra VGPRs and
// zv[64] stays register-resident (R2-R4 evidence: vector erow loads made the
// allocator spill zv to scratch -> 2.4x VALU inflation).
__global__ __launch_bounds__(256, 4)
void vq_main(const float* __restrict__ z, const float* __restrict__ emb,
             const float* __restrict__ enorm, int* __restrict__ counts,
             double* __restrict__ lacc, float* __restrict__ out) {
    __shared__ float dl[256];
    __shared__ int   il[256];
    __shared__ int   fidx[64];

    const int tid = threadIdx.x;
    const int l   = tid & 63;        // lane = position within block
    const int w   = tid >> 6;        // wave = codebook chunk
    const int n0  = blockIdx.x * 64; // first position of block (same image b)
    const int b   = n0 >> 12;
    const int hw0 = n0 & 4095;
    const int zoff = b * (64 * HW) + hw0 + l;      // element offset (fits in int)

    // load this position's 64-dim vector (coalesced across lanes per channel)
    float zv[64];
#pragma unroll
    for (int c = 0; c < 64; ++c) zv[c] = z[zoff + c * HW];

    const float szn = pairwise_sum_sq64(zv);

    // wave-uniform chunk base
    const int jbase = __builtin_amdgcn_readfirstlane(w * 256);

    float best = 3.4e38f;
    int   bi   = jbase;
    for (int jj = 0; jj < 256; ++jj) {
        const int j = jbase + jj;
        const int boff = j * 256;    // row byte offset
        i32x16 r0, r1, r2, r3;
        int en;
        // wave-uniform codebook row -> SGPRs (single-buffered; volatile order
        // prevents software-pipelining these past the consuming FMAs)
        asm volatile("s_load_dwordx16 %0, %1, %2" : "=s"(r0) : "s"(emb),   "s"(boff));
        asm volatile("s_load_dwordx16 %0, %1, %2" : "=s"(r1) : "s"(emb),   "s"(boff + 64));
        asm volatile("s_load_dwordx16 %0, %1, %2" : "=s"(r2) : "s"(emb),   "s"(boff + 128));
        asm volatile("s_load_dwordx16 %0, %1, %2" : "=s"(r3) : "s"(emb),   "s"(boff + 192));
        asm volatile("s_load_dword %0, %1, %2"    : "=s"(en) : "s"(enorm), "s"(j * 4));
        asm volatile("s_waitcnt lgkmcnt(0)" ::: "memory");
        __builtin_amdgcn_sched_barrier(0);   // rule #18: no hoisting past waitcnt

        // BLAS micro-kernel order: sequential k, single accumulator, FMA
        float acc = 0.0f;
#pragma unroll
        for (int c = 0; c < 16; ++c) acc = fmaf(zv[c],      __int_as_float(r0[c]), acc);
#pragma unroll
        for (int c = 0; c < 16; ++c) acc = fmaf(zv[16 + c], __int_as_float(r1[c]), acc);
#pragma unroll
        for (int c = 0; c < 16; ++c) acc = fmaf(zv[32 + c], __int_as_float(r2[c]), acc);
#pragma unroll
        for (int c = 0; c < 16; ++c) acc = fmaf(zv[48 + c], __int_as_float(r3[c]), acc);

        // dist = (||z||^2 + ||e||^2) - 2*dot  (2*acc exact => fusion harmless)
        const float dj = (szn + __int_as_float(en)) - 2.0f * acc;
        if (dj < best) { best = dj; bi = j; }   // strict < : first-min wins
    }
    dl[tid] = best;
    il[tid] = bi;
    __syncthreads();

    // cross-wave argmin reduce (ascending chunk order keeps lowest index on ties)
    if (w == 0) {
        float bd = dl[l];
        int   bx = il[l];
#pragma unroll
        for (int ww = 1; ww < 4; ++ww) {
            float dw = dl[ww * 64 + l];
            int   iw = il[ww * 64 + l];
            if (dw < bd) { bd = dw; bx = iw; }
        }
        fidx[l] = bx;
        atomicAdd(&counts[bx], 1);
        out[OUT_IDX + n0 + l] = (float)bx;    // indices as f32 values
    }
    __syncthreads();

    // one-hot rows: 64 rows x 1024 floats, float2 stores (base is 8B-aligned only)
    {
        float2* __restrict__ enc = (float2*)(out + OUT_ENC);
        const int c0 = tid * 2;
        const int c1 = (tid + 256) * 2;
        for (int r = 0; r < 64; ++r) {
            const int ir = fidx[r];
            const long long rowb = (long long)(n0 + r) * 512;
            float2 v0, v1;
            v0.x = (ir == c0)     ? 1.0f : 0.0f;
            v0.y = (ir == c0 + 1) ? 1.0f : 0.0f;
            v1.x = (ir == c1)     ? 1.0f : 0.0f;
            v1.y = (ir == c1 + 1) ? 1.0f : 0.0f;
            enc[rowb + tid]       = v0;
            enc[rowb + 256 + tid] = v1;
        }
    }

    // z_q_st = z + (z_q - z)  (two rounded f32 ops, same as reference).
    // thread (w,l): position l, channels w*16..w*16+15, using register zv.
    // Compile-time ww dispatch keeps zv indexing static (rule #20).
    const int myidx = fidx[l];
    double acc = 0.0;
#pragma unroll
    for (int ww = 0; ww < 4; ++ww) {
        if (w == ww) {
#pragma unroll
            for (int k = 0; k < 16; ++k) {
                const int c = ww * 16 + k;          // compile-time
                const float zc = zv[c];
                const float ec = emb[myidx * 64 + c];
                const float t  = __fsub_rn(ec, zc);   // z_q - z
                const float o  = __fadd_rn(zc, t);    // z + (z_q - z)
                out[OUT_ZQ + (long long)b * (64LL * HW) + (long long)c * HW + hw0 + l] = o;
                const float s = __fmul_rn(t, t);      // (z_q - z)^2 rounded f32
                acc += (double)s;
            }
        }
    }
    // wave-level f64 reduce, one atomic per wave
#pragma unroll
    for (int off = 32; off > 0; off >>= 1) acc += __shfl_down(acc, off);
    if (l == 0) atomicAdd(lacc, acc);
}

// K2: perplexity + loss finalize. 1 block x 1024 threads.
__global__ void vq_finalize(const int* __restrict__ counts,
                            const double* __restrict__ lacc,
                            float* __restrict__ out) {
    __shared__ float red[1024];
    const int t = threadIdx.x;
    const float p = (float)counts[t] * (1.0f / 65536.0f); // exact (count int, /2^16)
    const float term = p * logf(p + 1e-10f);
    red[t] = term;
    __syncthreads();
    for (int s = 512; s > 0; s >>= 1) {
        if (t < s) red[t] += red[t + s];
        __syncthreads();
    }
    if (t == 0) {
        out[OUT_PERP] = expf(-red[0]);
        out[OUT_LOSS] = (float)(BETA * (*lacc / 4194304.0));
    }
}

extern "C" void kernel_launch(void* const* d_in, const int* in_sizes, int n_in,
                              void* d_out, int out_size, void* d_ws, size_t ws_size,
                              hipStream_t stream) {
    const float* z   = (const float*)d_in[0];   // (16,64,64,64) f32
    const float* emb = (const float*)d_in[1];   // (1024,64) f32
    float* out = (float*)d_out;

    double* lacc  = (double*)d_ws;
    int*    cnts  = (int*)((char*)d_ws + 16);
    float*  enorm = (float*)((char*)d_ws + 16 + NE * sizeof(int));

    vq_prep<<<4, 256, 0, stream>>>(emb, enorm, cnts, lacc);
    vq_main<<<1024, 256, 0, stream>>>(z, emb, enorm, cnts, lacc, out);
    vq_finalize<<<1, 1024, 0, stream>>>(cnts, lacc, out);
}

// Round 6
// 197.090 us; speedup vs baseline: 1.2502x; 1.0004x over previous
//
#include <hip/hip_runtime.h>
#include <math.h>

// Problem constants
#define NPOS   65536        // 16*64*64 positions
#define NE     1024         // codebook size
#define EDIM   64
#define HW     4096         // 64*64
#define BETA   0.25

// Output layout (floats) in d_out, reference return order:
// loss(1), z_q_st(16*64*64*64), perplexity(1), min_encodings(65536*1024), indices(65536)
#define OUT_LOSS 0LL
#define OUT_ZQ   1LL
#define OUT_PERP 4194305LL
#define OUT_ENC  4194306LL
#define OUT_IDX  71303170LL

// numpy pairwise_sum for n=64 (8 accumulators, stride 8, tree combine) of squares.
__device__ __forceinline__ float pairwise_sum_sq64(const float v[64]) {
#pragma clang fp contract(off)
    float r[8];
#pragma unroll
    for (int k = 0; k < 8; ++k) r[k] = v[k] * v[k];
#pragma unroll
    for (int i = 8; i < 64; i += 8) {
#pragma unroll
        for (int k = 0; k < 8; ++k) {
            float s = v[i + k] * v[i + k];
            r[k] = r[k] + s;
        }
    }
    return ((r[0] + r[1]) + (r[2] + r[3])) + ((r[4] + r[5]) + (r[6] + r[7]));
}

// K0: codebook norms + transposed codebook + zero counts + zero loss accumulator
__global__ void vq_prep(const float* __restrict__ emb, float* __restrict__ enorm,
                        float* __restrict__ embT, int* __restrict__ counts,
                        double* __restrict__ lacc) {
    int t = blockIdx.x * 256 + threadIdx.x;   // 0..1023
    if (t < NE) {
        float v[64];
#pragma unroll
        for (int c = 0; c < 64; ++c) v[c] = emb[t * 64 + c];
        enorm[t] = pairwise_sum_sq64(v);
#pragma unroll
        for (int c = 0; c < 64; ++c) embT[c * NE + t] = v[c];  // coalesced
        counts[t] = 0;
    }
    if (t == 0) *lacc = 0.0;
}

// K1: main. grid = 1024 blocks x 256 threads.
// Block handles 64 consecutive positions (one lane each); 4 waves split the
// 1024 codes into 4 chunks of 256. Register tile = acc[32] (one j-tile of 32
// codes); z is STREAMED one channel at a time (zc, 1 live VGPR) and the
// codebook comes from the transposed copy embT[c][j] as a wave-uniform 128B
// row. Structural pressure ~45 VGPR: nothing for the allocator to spill.
// (R2-R5 evidence: any zv[64]-resident formulation gets reload-sunk, 2.4x
// VALU inflation. This formulation needs no zv array.)
__global__ __launch_bounds__(256, 4)
void vq_main(const float* __restrict__ z, const float* __restrict__ emb,
             const float* __restrict__ embT, const float* __restrict__ enorm,
             int* __restrict__ counts, double* __restrict__ lacc,
             float* __restrict__ out) {
    __shared__ float dl[256];
    __shared__ int   il[256];
    __shared__ int   fidx[64];

    const int tid = threadIdx.x;
    const int l   = tid & 63;        // lane = position within block
    const int w   = tid >> 6;        // wave = codebook chunk
    const int n0  = blockIdx.x * 64; // first position of block (same image b)
    const int b   = n0 >> 12;
    const int hw0 = n0 & 4095;
    const int zoff = b * (64 * HW) + hw0 + l;      // element offset (fits in int)

    // ||z||^2 pre-pass: stream the 64 channels, keep only 8 partials live
    float szn;
    {
#pragma clang fp contract(off)
        float r[8];
#pragma unroll
        for (int k = 0; k < 8; ++k) { float x = z[zoff + k * HW]; r[k] = x * x; }
        for (int i = 8; i < 64; i += 8) {
#pragma unroll
            for (int k = 0; k < 8; ++k) {
                float x = z[zoff + (i + k) * HW];
                float s = x * x;
                r[k] = r[k] + s;
            }
        }
        szn = ((r[0] + r[1]) + (r[2] + r[3])) + ((r[4] + r[5]) + (r[6] + r[7]));
    }

    // wave-uniform chunk base
    const int jbase = __builtin_amdgcn_readfirstlane(w * 256);

    float best = 3.4e38f;
    int   bi   = jbase;
#pragma clang loop unroll(disable)
    for (int t32 = 0; t32 < 8; ++t32) {           // 8 j-tiles of 32 codes
        const int j0 = jbase + t32 * 32;
        float acc[32];
#pragma unroll
        for (int u = 0; u < 32; ++u) acc[u] = 0.0f;

        // sequential k, single accumulator per code (BLAS micro-kernel order)
#pragma clang loop unroll_count(4)
        for (int c = 0; c < 64; ++c) {
            const float zc = z[zoff + c * HW];                 // L1-hit reload
            const float* __restrict__ er = embT + c * NE + j0; // wave-uniform row
#pragma unroll
            for (int u = 0; u < 32; ++u) acc[u] = fmaf(zc, er[u], acc[u]);
        }

        // dist = (||z||^2 + ||e||^2) - 2*dot ; ascending j, strict < (first min)
#pragma unroll
        for (int u = 0; u < 32; ++u) {
            const float dj = (szn + enorm[j0 + u]) - 2.0f * acc[u];
            if (dj < best) { best = dj; bi = j0 + u; }
        }
    }
    dl[tid] = best;
    il[tid] = bi;
    __syncthreads();

    // cross-wave argmin reduce (ascending chunk order keeps lowest index on ties)
    if (w == 0) {
        float bd = dl[l];
        int   bx = il[l];
#pragma unroll
        for (int ww = 1; ww < 4; ++ww) {
            float dw = dl[ww * 64 + l];
            int   iw = il[ww * 64 + l];
            if (dw < bd) { bd = dw; bx = iw; }
        }
        fidx[l] = bx;
        atomicAdd(&counts[bx], 1);
        out[OUT_IDX + n0 + l] = (float)bx;    // indices as f32 values
    }
    __syncthreads();

    // one-hot rows: 64 rows x 1024 floats, float2 stores (base is 8B-aligned only)
    {
        float2* __restrict__ enc = (float2*)(out + OUT_ENC);
        const int c0 = tid * 2;
        const int c1 = (tid + 256) * 2;
        for (int r = 0; r < 64; ++r) {
            const int ir = fidx[r];
            const long long rowb = (long long)(n0 + r) * 512;
            float2 v0, v1;
            v0.x = (ir == c0)     ? 1.0f : 0.0f;
            v0.y = (ir == c0 + 1) ? 1.0f : 0.0f;
            v1.x = (ir == c1)     ? 1.0f : 0.0f;
            v1.y = (ir == c1 + 1) ? 1.0f : 0.0f;
            enc[rowb + tid]       = v0;
            enc[rowb + 256 + tid] = v1;
        }
    }

    // z_q_st = z + (z_q - z)  (two rounded f32 ops, same as reference).
    // thread (w,l): position l, channels w*16..w*16+15 (fresh z loads = same bits)
    const int myidx = fidx[l];
    double acc = 0.0;
#pragma unroll
    for (int k = 0; k < 16; ++k) {
        const int c = w * 16 + k;
        const float zc = z[zoff + c * HW];
        const float ec = emb[myidx * 64 + c];
        const float t  = __fsub_rn(ec, zc);   // z_q - z
        const float o  = __fadd_rn(zc, t);    // z + (z_q - z)
        out[OUT_ZQ + (long long)b * (64LL * HW) + (long long)c * HW + hw0 + l] = o;
        const float s = __fmul_rn(t, t);      // (z_q - z)^2 rounded f32
        acc += (double)s;
    }
    // wave-level f64 reduce, one atomic per wave
#pragma unroll
    for (int off = 32; off > 0; off >>= 1) acc += __shfl_down(acc, off);
    if (l == 0) atomicAdd(lacc, acc);
}

// K2: perplexity + loss finalize. 1 block x 1024 threads.
__global__ void vq_finalize(const int* __restrict__ counts,
                            const double* __restrict__ lacc,
                            float* __restrict__ out) {
    __shared__ float red[1024];
    const int t = threadIdx.x;
    const float p = (float)counts[t] * (1.0f / 65536.0f); // exact (count int, /2^16)
    const float term = p * logf(p + 1e-10f);
    red[t] = term;
    __syncthreads();
    for (int s = 512; s > 0; s >>= 1) {
        if (t < s) red[t] += red[t + s];
        __syncthreads();
    }
    if (t == 0) {
        out[OUT_PERP] = expf(-red[0]);
        out[OUT_LOSS] = (float)(BETA * (*lacc / 4194304.0));
    }
}

extern "C" void kernel_launch(void* const* d_in, const int* in_sizes, int n_in,
                              void* d_out, int out_size, void* d_ws, size_t ws_size,
                              hipStream_t stream) {
    const float* z   = (const float*)d_in[0];   // (16,64,64,64) f32
    const float* emb = (const float*)d_in[1];   // (1024,64) f32
    float* out = (float*)d_out;

    double* lacc  = (double*)d_ws;
    int*    cnts  = (int*)((char*)d_ws + 16);
    float*  enorm = (float*)((char*)d_ws + 16 + NE * sizeof(int));
    float*  embT  = (float*)((char*)d_ws + 16 + NE * sizeof(int) + NE * sizeof(float));

    vq_prep<<<4, 256, 0, stream>>>(emb, enorm, embT, cnts, lacc);
    vq_main<<<1024, 256, 0, stream>>>(z, emb, embT, enorm, cnts, lacc, out);
    vq_finalize<<<1, 1024, 0, stream>>>(cnts, lacc, out);
}

// Round 7
// 195.079 us; speedup vs baseline: 1.2631x; 1.0103x over previous
//
#include <hip/hip_runtime.h>
#include <math.h>

// Problem constants
#define NPOS   65536        // 16*64*64 positions
#define NE     1024         // codebook size
#define EDIM   64
#define HW     4096         // 64*64
#define BETA   0.25

// Output layout (floats) in d_out, reference return order:
// loss(1), z_q_st(16*64*64*64), perplexity(1), min_encodings(65536*1024), indices(65536)
#define OUT_LOSS 0LL
#define OUT_ZQ   1LL
#define OUT_PERP 4194305LL
#define OUT_ENC  4194306LL
#define OUT_IDX  71303170LL

#define POSB 128            // positions per block
#define JT   128            // code-tile width (8 tiles cover 1024)

// numpy pairwise_sum for n=64 (8 accumulators, stride 8, tree combine) of squares.
__device__ __forceinline__ float pairwise_sum_sq64(const float v[64]) {
#pragma clang fp contract(off)
    float r[8];
#pragma unroll
    for (int k = 0; k < 8; ++k) r[k] = v[k] * v[k];
#pragma unroll
    for (int i = 8; i < 64; i += 8) {
#pragma unroll
        for (int k = 0; k < 8; ++k) {
            float s = v[i + k] * v[i + k];
            r[k] = r[k] + s;
        }
    }
    return ((r[0] + r[1]) + (r[2] + r[3])) + ((r[4] + r[5]) + (r[6] + r[7]));
}

// K0: codebook norms + transposed codebook + zero counts + zero loss accumulator
__global__ void vq_prep(const float* __restrict__ emb, float* __restrict__ enorm,
                        float* __restrict__ embT, int* __restrict__ counts,
                        double* __restrict__ lacc) {
    int t = blockIdx.x * 256 + threadIdx.x;   // 0..1023
    if (t < NE) {
        float v[64];
#pragma unroll
        for (int c = 0; c < 64; ++c) v[c] = emb[t * 64 + c];
        enorm[t] = pairwise_sum_sq64(v);
#pragma unroll
        for (int c = 0; c < 64; ++c) embT[c * NE + t] = v[c];  // coalesced
        counts[t] = 0;
    }
    if (t == 0) *lacc = 0.0;
}

// K1: main. grid = 512 blocks x 256 threads.
// Canonical LDS-tiled register-blocked GEMM (Section 5 anatomy, vector-ALU):
//   block tile: 128 pos x 128 codes per j-iteration (8 iterations = 1024 codes)
//   thread tile: 8 pos x 8 codes = 64 accumulators; per k: 4 ds_read_b128 / 64 FMA
// Bit-exactness: each dot = single accumulator, sequential k FMA (same op order
// as verified R2-R6 => identical bits => identical argmin).
__global__ __launch_bounds__(256, 2)
void vq_main(const float* __restrict__ z, const float* __restrict__ emb,
             const float* __restrict__ embT, const float* __restrict__ enorm,
             int* __restrict__ counts, double* __restrict__ lacc,
             float* __restrict__ out) {
    __shared__ float z_lds[64 * POSB];      // [c][p]
    __shared__ float e_lds[64 * JT];        // [c][q]
    __shared__ float enorm_lds[NE];
    __shared__ float szn_lds[POSB];
    __shared__ float run_d[POSB];
    __shared__ int   run_j[POSB];

    const int tid   = threadIdx.x;
    const int tpos  = tid >> 4;       // 0..15 -> positions tpos*8..+7
    const int tcode = tid & 15;       // 0..15 -> codes    tcode*8..+7 (within tile)
    const int n0    = blockIdx.x * POSB;
    const int b     = n0 >> 12;
    const int hw0   = n0 & 4095;
    const int zbase = b * (64 * HW) + hw0;

    // ---- stage z tile (64 c x 128 pos), float4 both sides ----
#pragma unroll
    for (int it = 0; it < 8; ++it) {
        const int idx4 = it * 256 + tid;          // 0..2047 float4s
        const int c    = idx4 >> 5;               // 32 float4 per c-row
        const int p4   = idx4 & 31;
        const float4 v = *(const float4*)(z + zbase + c * HW + p4 * 4);
        *(float4*)(&z_lds[c * POSB + p4 * 4]) = v;
    }
    // ---- stage enorm + init running argmin ----
#pragma unroll
    for (int it = 0; it < 4; ++it) enorm_lds[it * 256 + tid] = enorm[it * 256 + tid];
    if (tid < POSB) { run_d[tid] = 3.4e38f; run_j[tid] = 0; }
    __syncthreads();

    // ---- szn per position from z_lds (bit-identical values, numpy pairwise order) ----
    if (tid < POSB) {
#pragma clang fp contract(off)
        float r[8];
#pragma unroll
        for (int k = 0; k < 8; ++k) { float x = z_lds[k * POSB + tid]; r[k] = x * x; }
#pragma unroll
        for (int i = 8; i < 64; i += 8) {
#pragma unroll
            for (int k = 0; k < 8; ++k) {
                float x = z_lds[(i + k) * POSB + tid];
                float s = x * x;
                r[k] = r[k] + s;
            }
        }
        szn_lds[tid] = ((r[0] + r[1]) + (r[2] + r[3])) + ((r[4] + r[5]) + (r[6] + r[7]));
    }
    __syncthreads();

    // ---- main loop over 8 code tiles ----
    for (int jo = 0; jo < 8; ++jo) {
        const int j0 = jo * JT;

        // stage e tile (64 c x 128 codes) from transposed codebook
#pragma unroll
        for (int it = 0; it < 8; ++it) {
            const int idx4 = it * 256 + tid;
            const int c    = idx4 >> 5;
            const int q4   = idx4 & 31;
            const float4 v = *(const float4*)(embT + c * NE + j0 + q4 * 4);
            *(float4*)(&e_lds[c * JT + q4 * 4]) = v;
        }
        __syncthreads();

        float acc[8][8];
#pragma unroll
        for (int i = 0; i < 8; ++i)
#pragma unroll
            for (int u = 0; u < 8; ++u) acc[i][u] = 0.0f;

        // k-loop: sequential k, single accumulator per (pos,code) pair
#pragma unroll 2
        for (int c = 0; c < 64; ++c) {
            const float4 za = *(const float4*)(&z_lds[c * POSB + tpos * 8]);
            const float4 zb = *(const float4*)(&z_lds[c * POSB + tpos * 8 + 4]);
            const float4 ea = *(const float4*)(&e_lds[c * JT + tcode * 8]);
            const float4 eb = *(const float4*)(&e_lds[c * JT + tcode * 8 + 4]);
            const float zf[8] = {za.x, za.y, za.z, za.w, zb.x, zb.y, zb.z, zb.w};
            const float ef[8] = {ea.x, ea.y, ea.z, ea.w, eb.x, eb.y, eb.z, eb.w};
#pragma unroll
            for (int i = 0; i < 8; ++i)
#pragma unroll
                for (int u = 0; u < 8; ++u)
                    acc[i][u] = fmaf(zf[i], ef[u], acc[i][u]);
        }

        // distances + tie-correct argmin reduce
#pragma unroll
        for (int i = 0; i < 8; ++i) {
            const int p = tpos * 8 + i;
            const float sz = szn_lds[p];
            float bd = 3.4e38f;
            int   bj = 0;
#pragma unroll
            for (int u = 0; u < 8; ++u) {
                const int j = j0 + tcode * 8 + u;
                const float dj = (sz + enorm_lds[j]) - 2.0f * acc[i][u];
                if (dj < bd) { bd = dj; bj = j; }   // ascending u, strict <
            }
            // reduce across the 16 tcode-lanes (quarter-wave); ties -> lower j
#pragma unroll
            for (int m = 1; m < 16; m <<= 1) {
                const float od = __shfl_xor(bd, m, 64);
                const int   oj = __shfl_xor(bj, m, 64);
                if (od < bd || (od == bd && oj < bj)) { bd = od; bj = oj; }
            }
            if (tcode == 0) {
                // ascending tile order + strict < keeps earliest index on ties
                if (bd < run_d[p]) { run_d[p] = bd; run_j[p] = bj; }
            }
        }
        __syncthreads();   // e_lds reuse + run_* visibility
    }

    // ---- outputs ----
    if (tid < POSB) {
        const int j = run_j[tid];
        atomicAdd(&counts[j], 1);
        out[OUT_IDX + n0 + tid] = (float)j;    // indices as f32 values
    }

    // one-hot rows: 128 rows x 1024 floats, float2 stores
    {
        float2* __restrict__ enc = (float2*)(out + OUT_ENC);
        const int c0 = tid * 2;
        const int c1 = (tid + 256) * 2;
        for (int r = 0; r < POSB; ++r) {
            const int ir = run_j[r];
            const long long rowb = (long long)(n0 + r) * 512;
            float2 v0, v1;
            v0.x = (ir == c0)     ? 1.0f : 0.0f;
            v0.y = (ir == c0 + 1) ? 1.0f : 0.0f;
            v1.x = (ir == c1)     ? 1.0f : 0.0f;
            v1.y = (ir == c1 + 1) ? 1.0f : 0.0f;
            enc[rowb + tid]       = v0;
            enc[rowb + 256 + tid] = v1;
        }
    }

    // z_q_st = z + (z_q - z) (two rounded f32 ops, verified pattern).
    // thread: pos = tid&127, channels (tid>>7)*32 .. +31; z from z_lds (same bits).
    {
        const int pos = tid & 127;
        const int half = tid >> 7;              // 0 or 1
        const int myj = run_j[pos];
        double acc2 = 0.0;
#pragma unroll
        for (int k = 0; k < 32; ++k) {
            const int c = half * 32 + k;
            const float zc = z_lds[c * POSB + pos];
            const float ec = emb[myj * 64 + c];
            const float t  = __fsub_rn(ec, zc);   // z_q - z
            const float o  = __fadd_rn(zc, t);    // z + (z_q - z)
            out[OUT_ZQ + (long long)b * (64LL * HW) + (long long)c * HW + hw0 + pos] = o;
            const float s = __fmul_rn(t, t);      // (z_q - z)^2 rounded f32
            acc2 += (double)s;
        }
        // wave-level f64 reduce, one atomic per wave
#pragma unroll
        for (int off = 32; off > 0; off >>= 1) acc2 += __shfl_down(acc2, off);
        if ((tid & 63) == 0) atomicAdd(lacc, acc2);
    }
}

// K2: perplexity + loss finalize. 1 block x 1024 threads.
__global__ void vq_finalize(const int* __restrict__ counts,
                            const double* __restrict__ lacc,
                            float* __restrict__ out) {
    __shared__ float red[1024];
    const int t = threadIdx.x;
    const float p = (float)counts[t] * (1.0f / 65536.0f); // exact (count int, /2^16)
    const float term = p * logf(p + 1e-10f);
    red[t] = term;
    __syncthreads();
    for (int s = 512; s > 0; s >>= 1) {
        if (t < s) red[t] += red[t + s];
        __syncthreads();
    }
    if (t == 0) {
        out[OUT_PERP] = expf(-red[0]);
        out[OUT_LOSS] = (float)(BETA * (*lacc / 4194304.0));
    }
}

extern "C" void kernel_launch(void* const* d_in, const int* in_sizes, int n_in,
                              void* d_out, int out_size, void* d_ws, size_t ws_size,
                              hipStream_t stream) {
    const float* z   = (const float*)d_in[0];   // (16,64,64,64) f32
    const float* emb = (const float*)d_in[1];   // (1024,64) f32
    float* out = (float*)d_out;

    double* lacc  = (double*)d_ws;
    int*    cnts  = (int*)((char*)d_ws + 16);
    float*  enorm = (float*)((char*)d_ws + 16 + NE * sizeof(int));
    float*  embT  = (float*)((char*)d_ws + 16 + NE * sizeof(int) + NE * sizeof(float));

    vq_prep<<<4, 256, 0, stream>>>(emb, enorm, embT, cnts, lacc);
    vq_main<<<512, 256, 0, stream>>>(z, emb, embT, enorm, cnts, lacc, out);
    vq_finalize<<<1, 1024, 0, stream>>>(cnts, lacc, out);
}